// Round 5
// baseline (1110.154 us; speedup 1.0000x reference)
//
#include <hip/hip_runtime.h>

// GCN 2-layer for MI355X (gfx950). fp32 GEMM, bf16 intermediates, fp32 out.
// out[v] = relu( dinv[v]*( g[v] + sum_{u->v} g[u] ) + b ),  g = dinv .* (x @ W)
//
// R4->R5: CSR eliminated. Aggregation = block-per-bucket LDS accumulator fed
// directly from the bucket-partitioned edge buffer. Zero global atomics.
// Pipeline (10 kernels):
//   bucket_hist -> [3-stage scan of hist] -> partition -> bucket_dinv
//   -> gemm128 -> agg_bucket<128> -> gemm64 -> agg_bucket<64>

#define NPB 64    // nodes per bucket (power of 2)
#define PB  128   // partition chunk-blocks

typedef unsigned short ushort_t;
typedef unsigned int uint_t;

__device__ inline float bf2f_lo(uint_t u) { return __uint_as_float(u << 16); }
__device__ inline float bf2f_hi(uint_t u) { return __uint_as_float(u & 0xffff0000u); }
__device__ inline ushort_t f2bf(float f) {   // round-to-nearest-even
    uint_t x = __float_as_uint(f);
    uint_t r = x + 0x7fffu + ((x >> 16) & 1u);
    return (ushort_t)(r >> 16);
}

// ---------- scan machinery (for the flat bucket histogram) ----------

__global__ __launch_bounds__(256) void block_sum_kernel(const int* __restrict__ a, int L,
                                                        int* __restrict__ bsum) {
    __shared__ int red[256];
    int t = threadIdx.x;
    int base = blockIdx.x * 1024 + t * 4;
    int s = 0;
    if (base + 3 < L) {
        int4 v = *(const int4*)&a[base];
        s = v.x + v.y + v.z + v.w;
    } else {
        for (int i = 0; i < 4; ++i) if (base + i < L) s += a[base + i];
    }
    red[t] = s;
    __syncthreads();
    for (int off = 128; off > 0; off >>= 1) {
        if (t < off) red[t] += red[t + off];
        __syncthreads();
    }
    if (t == 0) bsum[blockIdx.x] = red[0];
}

__global__ __launch_bounds__(1024) void scan_bsum_kernel(int* __restrict__ bsum, int nb,
                                                         int* __restrict__ total_slot) {
    __shared__ int sh[1024];
    int t = threadIdx.x;
    int v = (t < nb) ? bsum[t] : 0;
    sh[t] = v;
    __syncthreads();
    for (int off = 1; off < 1024; off <<= 1) {
        int w = (t >= off) ? sh[t - off] : 0;
        __syncthreads();
        sh[t] += w;
        __syncthreads();
    }
    if (t < nb) bsum[t] = sh[t];
    if (t == nb - 1) *total_slot = sh[t];
}

__global__ __launch_bounds__(256) void local_scan_apply_kernel(int* __restrict__ arr, int L,
                                                               const int* __restrict__ bsum_incl) {
    __shared__ int tsum[256];
    int b = blockIdx.x, t = threadIdx.x;
    int base = b * 1024 + t * 4;
    int v[4];
    int s = 0;
    #pragma unroll
    for (int i = 0; i < 4; ++i) {
        int idx = base + i;
        v[i] = (idx < L) ? arr[idx] : 0;
        s += v[i];
    }
    tsum[t] = s;
    __syncthreads();
    for (int off = 1; off < 256; off <<= 1) {
        int w = (t >= off) ? tsum[t - off] : 0;
        __syncthreads();
        tsum[t] += w;
        __syncthreads();
    }
    int excl = (t == 0 ? 0 : tsum[t - 1]) + (b == 0 ? 0 : bsum_incl[b - 1]);
    #pragma unroll
    for (int i = 0; i < 4; ++i) {
        int idx = base + i;
        if (idx < L) {
            arr[idx] = excl;
            excl += v[i];
        }
    }
}

// ---------- radix partition (no global atomics) ----------

__global__ __launch_bounds__(256) void bucket_hist_kernel(const int* __restrict__ dst, int e,
                                                          int epb, int K,
                                                          int* __restrict__ hist) {
    __shared__ int lh[1024];
    int t = threadIdx.x, b = blockIdx.x;
    for (int k = t; k < K; k += 256) lh[k] = 0;
    __syncthreads();
    int lo = b * epb, hi = min(lo + epb, e);
    for (int i = lo + t; i < hi; i += 256) atomicAdd(&lh[dst[i] >> 6], 1);
    __syncthreads();
    for (int k = t; k < K; k += 256) hist[k * PB + b] = lh[k];
}

// scatter packed (src | dlocal<<16) into bucket regions (requires n <= 65536)
__global__ __launch_bounds__(256) void partition_kernel(const int* __restrict__ src,
                                                        const int* __restrict__ dst, int e,
                                                        int epb, int K,
                                                        const int* __restrict__ hist,
                                                        uint_t* __restrict__ ebuf) {
    __shared__ int loff[1024];
    int t = threadIdx.x, b = blockIdx.x;
    for (int k = t; k < K; k += 256) loff[k] = hist[k * PB + b];
    __syncthreads();
    int lo = b * epb, hi = min(lo + epb, e);
    for (int i = lo + t; i < hi; i += 256) {
        int d = dst[i];
        int k = d >> 6;
        int pos = atomicAdd(&loff[k], 1);   // LDS atomic only
        ebuf[pos] = (uint_t)src[i] | ((uint_t)(d & (NPB - 1)) << 16);
    }
}

// per-bucket degrees -> dinv (no scan, no cnt array)
__global__ __launch_bounds__(256) void bucket_dinv_kernel(const uint_t* __restrict__ ebuf,
                                                          const int* __restrict__ hist,
                                                          int e, int K, int n,
                                                          float* __restrict__ dinv) {
    __shared__ int c64[NPB];
    int t = threadIdx.x, k = blockIdx.x;
    if (t < NPB) c64[t] = 0;
    __syncthreads();
    int lo = hist[k * PB];
    int hi = (k + 1 < K) ? hist[(k + 1) * PB] : e;
    for (int i = lo + t; i < hi; i += 256) atomicAdd(&c64[(ebuf[i] >> 16) & (NPB - 1)], 1);
    __syncthreads();
    int node = k * NPB + t;
    if (t < NPB && node < n) dinv[node] = rsqrtf((float)(c64[t] + 1));  // +1 self loop
}

// ---------- GEMM: C_bf16[n,COLS] = dinv[row] * (A[n,128] @ W[128,COLS]) ----------
#define K_DIM 128
template <int COLS>
__global__ __launch_bounds__(256) void gemm_scale_kernel(const float* __restrict__ A,
                                                         const float* __restrict__ W,
                                                         const float* __restrict__ dinv,
                                                         ushort_t* __restrict__ out, int n) {
    constexpr int CG  = COLS / 4;
    constexpr int RG  = 256 / CG;
    constexpr int RPT = 64 / RG;
    __shared__ float Asl[64][132];
    int t    = threadIdx.x;
    int row0 = blockIdx.x * 64;

    #pragma unroll
    for (int it = 0; it < 8; ++it) {
        int idx = (it * 256 + t) * 4;
        int r = idx >> 7;
        int k = idx & 127;
        int gr = row0 + r;
        float4 v = {0.f, 0.f, 0.f, 0.f};
        if (gr < n) v = *(const float4*)&A[gr * K_DIM + k];
        *(float4*)&Asl[r][k] = v;
    }
    __syncthreads();

    int cg = t % CG, rg = t / CG;
    int c0 = cg * 4;
    float acc[RPT][4];
    #pragma unroll
    for (int i = 0; i < RPT; ++i)
        for (int j = 0; j < 4; ++j) acc[i][j] = 0.f;

    for (int k = 0; k < K_DIM; ++k) {
        float4 w = *(const float4*)&W[k * COLS + c0];
        #pragma unroll
        for (int i = 0; i < RPT; ++i) {
            float a = Asl[rg * RPT + i][k];
            acc[i][0] = fmaf(a, w.x, acc[i][0]);
            acc[i][1] = fmaf(a, w.y, acc[i][1]);
            acc[i][2] = fmaf(a, w.z, acc[i][2]);
            acc[i][3] = fmaf(a, w.w, acc[i][3]);
        }
    }

    #pragma unroll
    for (int i = 0; i < RPT; ++i) {
        int r = row0 + rg * RPT + i;
        if (r < n) {
            float s = dinv[r];
            ushort4 o;
            o.x = f2bf(acc[i][0] * s);
            o.y = f2bf(acc[i][1] * s);
            o.z = f2bf(acc[i][2] * s);
            o.w = f2bf(acc[i][3] * s);
            *(ushort4*)&out[r * COLS + c0] = o;
        }
    }
}

// ---------- aggregation: block-per-bucket, LDS fp32 accumulator ----------
// Each thread: one edge-slice (8 feats = 16B of bf16). ds_add_f32 into acc.
template <int COLS>
__global__ __launch_bounds__(256) void aggregate_bucket_kernel(const ushort_t* __restrict__ g,
                                                               const uint_t* __restrict__ ebuf,
                                                               const int* __restrict__ hist,
                                                               const float* __restrict__ dinv,
                                                               const float* __restrict__ bias,
                                                               float* __restrict__ out,
                                                               int e, int K, int n) {
    constexpr int LPE = COLS / 8;     // lanes per edge: 16 (128c) or 8 (64c)
    constexpr int EPI = 256 / LPE;    // edges per block-iteration: 16 or 32
    constexpr int STR = COLS + 4;     // pad: breaks systematic bank conflicts
    __shared__ float acc[NPB * STR];

    int t = threadIdx.x, k = blockIdx.x;
    for (int i = t; i < NPB * STR; i += 256) acc[i] = 0.f;
    __syncthreads();

    int lo = hist[k * PB];
    int hi = (k + 1 < K) ? hist[(k + 1) * PB] : e;
    int epi = t / LPE;                // edge slot within iteration
    int f   = t % LPE;                // feature group (8 feats)

    #pragma unroll 4
    for (int j = lo + epi; j < hi; j += EPI) {
        uint_t u = ebuf[j];           // coalesced within the bucket window
        int srcv = (int)(u & 0xffffu);
        int dl   = (int)((u >> 16) & (NPB - 1));
        uint4 m = *(const uint4*)&g[(size_t)srcv * COLS + f * 8];
        float* a = &acc[dl * STR + f * 8];
        atomicAdd(&a[0], bf2f_lo(m.x)); atomicAdd(&a[1], bf2f_hi(m.x));
        atomicAdd(&a[2], bf2f_lo(m.y)); atomicAdd(&a[3], bf2f_hi(m.y));
        atomicAdd(&a[4], bf2f_lo(m.z)); atomicAdd(&a[5], bf2f_hi(m.z));
        atomicAdd(&a[6], bf2f_lo(m.w)); atomicAdd(&a[7], bf2f_hi(m.w));
    }
    __syncthreads();

    // epilogue: out[v] = relu(dinv[v]*(acc + g_self) + bias)
    for (int unit = t; unit < NPB * LPE; unit += 256) {
        int nd = unit / LPE;
        int fg = unit % LPE;
        int v = k * NPB + nd;
        if (v >= n) continue;
        float dv = dinv[v];
        uint4 m = *(const uint4*)&g[(size_t)v * COLS + fg * 8];   // self row
        float4 b0 = *(const float4*)&bias[fg * 8];
        float4 b1 = *(const float4*)&bias[fg * 8 + 4];
        float4 a0 = *(const float4*)&acc[nd * STR + fg * 8];
        float4 a1 = *(const float4*)&acc[nd * STR + fg * 8 + 4];
        float4 o0 = {fmaxf(fmaf(a0.x + bf2f_lo(m.x), dv, b0.x), 0.f),
                     fmaxf(fmaf(a0.y + bf2f_hi(m.x), dv, b0.y), 0.f),
                     fmaxf(fmaf(a0.z + bf2f_lo(m.y), dv, b0.z), 0.f),
                     fmaxf(fmaf(a0.w + bf2f_hi(m.y), dv, b0.w), 0.f)};
        float4 o1 = {fmaxf(fmaf(a1.x + bf2f_lo(m.z), dv, b1.x), 0.f),
                     fmaxf(fmaf(a1.y + bf2f_hi(m.z), dv, b1.y), 0.f),
                     fmaxf(fmaf(a1.z + bf2f_lo(m.w), dv, b1.z), 0.f),
                     fmaxf(fmaf(a1.w + bf2f_hi(m.w), dv, b1.w), 0.f)};
        *(float4*)&out[(size_t)v * COLS + fg * 8] = o0;
        *(float4*)&out[(size_t)v * COLS + fg * 8 + 4] = o1;
    }
}

extern "C" void kernel_launch(void* const* d_in, const int* in_sizes, int n_in,
                              void* d_out, int out_size, void* d_ws, size_t ws_size,
                              hipStream_t stream) {
    const float* x  = (const float*)d_in[0];
    const int*   ei = (const int*)d_in[1];   // [2, E] int32
    const float* W1 = (const float*)d_in[2];
    const float* b1 = (const float*)d_in[3];
    const float* W2 = (const float*)d_in[4];
    const float* b2 = (const float*)d_in[5];
    float* out = (float*)d_out;

    const int n = in_sizes[0] / 128;   // 50000 (<= 65536 required for packing)
    const int e = in_sizes[1] / 2;     // 800000
    const int* src = ei;
    const int* dst = ei + e;
    const int K   = (n + NPB - 1) / NPB;       // 782 buckets
    const int epb = (e + PB - 1) / PB;         // edges per chunk-block
    const int L   = K * PB;                    // flat histogram length

    char* ws = (char*)d_ws;
    size_t off = 0;
    auto carve = [&](size_t bytes) -> void* {
        void* p = ws + off;
        off = (off + bytes + 255) & ~(size_t)255;
        return p;
    };
    int*      hist   = (int*)     carve((size_t)L * 4);
    int*      bsum   = (int*)     carve((size_t)1024 * 4);
    int*      htotal = (int*)     carve((size_t)4);
    float*    dinv   = (float*)   carve((size_t)n * 4);
    uint_t*   ebuf   = (uint_t*)  carve((size_t)e * 4);
    ushort_t* g1     = (ushort_t*)carve((size_t)n * 128 * 2);
    float*    h2     = (float*)   carve((size_t)n * 128 * 4);
    ushort_t* g2     = (ushort_t*)carve((size_t)n * 64 * 2);
    (void)ws_size;

    const int nbL = (L + 1023) / 1024;

    // --- partition + dinv (zero global atomics, zero memsets) ---
    bucket_hist_kernel<<<PB, 256, 0, stream>>>(dst, e, epb, K, hist);
    block_sum_kernel<<<nbL, 256, 0, stream>>>(hist, L, bsum);
    scan_bsum_kernel<<<1, 1024, 0, stream>>>(bsum, nbL, htotal);
    local_scan_apply_kernel<<<nbL, 256, 0, stream>>>(hist, L, bsum);
    partition_kernel<<<PB, 256, 0, stream>>>(src, dst, e, epb, K, hist, ebuf);
    bucket_dinv_kernel<<<K, 256, 0, stream>>>(ebuf, hist, e, K, n, dinv);

    // --- layers ---
    const int gblocks = (n + 63) / 64;
    gemm_scale_kernel<128><<<gblocks, 256, 0, stream>>>(x, W1, dinv, g1, n);
    aggregate_bucket_kernel<128><<<K, 256, 0, stream>>>(g1, ebuf, hist, dinv, b1, h2, e, K, n);
    gemm_scale_kernel<64><<<gblocks, 256, 0, stream>>>(h2, W2, dinv, g2, n);
    aggregate_bucket_kernel<64><<<K, 256, 0, stream>>>(g2, ebuf, hist, dinv, b2, out, e, K, n);
}

// Round 7
// 163.776 us; speedup vs baseline: 6.7785x; 6.7785x over previous
//
#include <hip/hip_runtime.h>

// GCN 2-layer for MI355X (gfx950). fp32 GEMM, bf16 intermediates, fp32 out.
// out[v] = relu( dinv[v]*( g[v] + sum_{u->v} g[u] ) + b ),  g = dinv .* (x @ W)
//
// EXACT R4 revert. R6's fused bucket_fill (in-kernel shfl-scan -> rowstart)
// intermittently lost an edge under graph replay (post-timing absmax 5.6e-2
// ~= one dropped edge: dinv*|g2| ~ 0.06). R4's un-fused pipeline passed the
// full harness incl. post-timing replay revalidation. Fused variant is
// quarantined until the nondeterminism is understood.
// R3 lesson: global atomics are the enemy. Zero global atomics here.
// R5 lesson: LDS-accumulator scatter aggregation is 12x slower than per-wave
// gather; aggregation stays gather-form (4-8 rows in flight per wave).

#define NPB 64    // nodes per bucket (power of 2)
#define PB  128   // partition chunk-blocks

typedef unsigned short ushort_t;
typedef unsigned int uint_t;

__device__ inline float bf2f_lo(uint_t u) { return __uint_as_float(u << 16); }
__device__ inline float bf2f_hi(uint_t u) { return __uint_as_float(u & 0xffff0000u); }
__device__ inline ushort_t f2bf(float f) {   // round-to-nearest-even
    uint_t x = __float_as_uint(f);
    uint_t r = x + 0x7fffu + ((x >> 16) & 1u);
    return (ushort_t)(r >> 16);
}

// ---------- generic 3-stage exclusive scan machinery ----------

__global__ __launch_bounds__(256) void block_sum_kernel(const int* __restrict__ a, int L,
                                                        int* __restrict__ bsum) {
    __shared__ int red[256];
    int t = threadIdx.x;
    int base = blockIdx.x * 1024 + t * 4;
    int s = 0;
    if (base + 3 < L) {
        int4 v = *(const int4*)&a[base];
        s = v.x + v.y + v.z + v.w;
    } else {
        for (int i = 0; i < 4; ++i) if (base + i < L) s += a[base + i];
    }
    red[t] = s;
    __syncthreads();
    for (int off = 128; off > 0; off >>= 1) {
        if (t < off) red[t] += red[t + off];
        __syncthreads();
    }
    if (t == 0) bsum[blockIdx.x] = red[0];
}

__global__ __launch_bounds__(1024) void scan_bsum_kernel(int* __restrict__ bsum, int nb,
                                                         int* __restrict__ total_slot) {
    __shared__ int sh[1024];
    int t = threadIdx.x;
    int v = (t < nb) ? bsum[t] : 0;
    sh[t] = v;
    __syncthreads();
    for (int off = 1; off < 1024; off <<= 1) {
        int w = (t >= off) ? sh[t - off] : 0;
        __syncthreads();
        sh[t] += w;
        __syncthreads();
    }
    if (t < nb) bsum[t] = sh[t];
    if (t == nb - 1) *total_slot = sh[t];
}

// node variant: reads cnt, writes exclusive rowstart + dinv
__global__ __launch_bounds__(256) void local_scan_kernel(const int* __restrict__ cnt, int n,
                                                         const int* __restrict__ bsum_incl,
                                                         int* __restrict__ rowstart,
                                                         float* __restrict__ dinv) {
    __shared__ int tsum[256];
    int b = blockIdx.x, t = threadIdx.x;
    int base = b * 1024 + t * 4;
    int v[4];
    int s = 0;
    #pragma unroll
    for (int i = 0; i < 4; ++i) {
        int idx = base + i;
        v[i] = (idx < n) ? cnt[idx] : 0;
        s += v[i];
    }
    tsum[t] = s;
    __syncthreads();
    for (int off = 1; off < 256; off <<= 1) {
        int w = (t >= off) ? tsum[t - off] : 0;
        __syncthreads();
        tsum[t] += w;
        __syncthreads();
    }
    int excl = (t == 0 ? 0 : tsum[t - 1]) + (b == 0 ? 0 : bsum_incl[b - 1]);
    #pragma unroll
    for (int i = 0; i < 4; ++i) {
        int idx = base + i;
        if (idx < n) {
            rowstart[idx] = excl;
            excl += v[i];
            dinv[idx] = rsqrtf((float)(v[i] + 1));   // +1 self loop
        }
    }
}

// in-place variant for the flat histogram (no dinv)
__global__ __launch_bounds__(256) void local_scan_apply_kernel(int* __restrict__ arr, int L,
                                                               const int* __restrict__ bsum_incl) {
    __shared__ int tsum[256];
    int b = blockIdx.x, t = threadIdx.x;
    int base = b * 1024 + t * 4;
    int v[4];
    int s = 0;
    #pragma unroll
    for (int i = 0; i < 4; ++i) {
        int idx = base + i;
        v[i] = (idx < L) ? arr[idx] : 0;
        s += v[i];
    }
    tsum[t] = s;
    __syncthreads();
    for (int off = 1; off < 256; off <<= 1) {
        int w = (t >= off) ? tsum[t - off] : 0;
        __syncthreads();
        tsum[t] += w;
        __syncthreads();
    }
    int excl = (t == 0 ? 0 : tsum[t - 1]) + (b == 0 ? 0 : bsum_incl[b - 1]);
    #pragma unroll
    for (int i = 0; i < 4; ++i) {
        int idx = base + i;
        if (idx < L) {
            arr[idx] = excl;
            excl += v[i];
        }
    }
}

// ---------- radix partition (no global atomics) ----------

// P1: per chunk-block LDS histogram over buckets -> hist[k*PB + b]
__global__ __launch_bounds__(256) void bucket_hist_kernel(const int* __restrict__ dst, int e,
                                                          int epb, int K,
                                                          int* __restrict__ hist) {
    __shared__ int lh[1024];
    int t = threadIdx.x, b = blockIdx.x;
    for (int k = t; k < K; k += 256) lh[k] = 0;
    __syncthreads();
    int lo = b * epb, hi = min(lo + epb, e);
    for (int i = lo + t; i < hi; i += 256) atomicAdd(&lh[dst[i] >> 6], 1);
    __syncthreads();
    for (int k = t; k < K; k += 256) hist[k * PB + b] = lh[k];
}

// P3: scatter packed (src | dlocal<<16) into bucket regions (requires n <= 65536)
__global__ __launch_bounds__(256) void partition_kernel(const int* __restrict__ src,
                                                        const int* __restrict__ dst, int e,
                                                        int epb, int K,
                                                        const int* __restrict__ hist,
                                                        uint_t* __restrict__ ebuf) {
    __shared__ int loff[1024];
    int t = threadIdx.x, b = blockIdx.x;
    for (int k = t; k < K; k += 256) loff[k] = hist[k * PB + b];
    __syncthreads();
    int lo = b * epb, hi = min(lo + epb, e);
    for (int i = lo + t; i < hi; i += 256) {
        int d = dst[i];
        int k = d >> 6;
        int pos = atomicAdd(&loff[k], 1);   // LDS atomic only
        ebuf[pos] = (uint_t)src[i] | ((uint_t)(d & (NPB - 1)) << 16);
    }
}

// per-bucket node counts (replaces 800k-global-atomic count_edges)
__global__ __launch_bounds__(256) void bucket_count_kernel(const uint_t* __restrict__ ebuf,
                                                           const int* __restrict__ hist,
                                                           int e, int K, int n,
                                                           int* __restrict__ cnt) {
    __shared__ int c64[NPB];
    int t = threadIdx.x, k = blockIdx.x;
    if (t < NPB) c64[t] = 0;
    __syncthreads();
    int lo = hist[k * PB];
    int hi = (k + 1 < K) ? hist[(k + 1) * PB] : e;
    for (int i = lo + t; i < hi; i += 256) atomicAdd(&c64[(ebuf[i] >> 16) & (NPB - 1)], 1);
    __syncthreads();
    int node = k * NPB + t;
    if (t < NPB && node < n) cnt[node] = c64[t];
}

// per-bucket CSR fill: writes land in the bucket's ~4KB csr window
__global__ __launch_bounds__(256) void bucket_fill_kernel(const uint_t* __restrict__ ebuf,
                                                          const int* __restrict__ hist,
                                                          const int* __restrict__ rowstart,
                                                          int e, int K, int n,
                                                          int* __restrict__ csr_src) {
    __shared__ int rs[NPB];
    __shared__ int c64[NPB];
    int t = threadIdx.x, k = blockIdx.x;
    if (t < NPB) {
        int node = k * NPB + t;
        rs[t] = (node < n) ? rowstart[node] : 0;
        c64[t] = 0;
    }
    __syncthreads();
    int lo = hist[k * PB];
    int hi = (k + 1 < K) ? hist[(k + 1) * PB] : e;
    for (int i = lo + t; i < hi; i += 256) {
        uint_t u = ebuf[i];
        int dl = (u >> 16) & (NPB - 1);
        int slot = rs[dl] + atomicAdd(&c64[dl], 1);   // LDS atomic only
        csr_src[slot] = (int)(u & 0xffffu);
    }
}

// ---------- GEMM: C_bf16[n,COLS] = dinv[row] * (A[n,128] @ W[128,COLS]) ----------
#define K_DIM 128
template <int COLS>
__global__ __launch_bounds__(256) void gemm_scale_kernel(const float* __restrict__ A,
                                                         const float* __restrict__ W,
                                                         const float* __restrict__ dinv,
                                                         ushort_t* __restrict__ out, int n) {
    constexpr int CG  = COLS / 4;
    constexpr int RG  = 256 / CG;
    constexpr int RPT = 64 / RG;
    __shared__ float Asl[64][132];
    int t    = threadIdx.x;
    int row0 = blockIdx.x * 64;

    #pragma unroll
    for (int it = 0; it < 8; ++it) {
        int idx = (it * 256 + t) * 4;
        int r = idx >> 7;
        int k = idx & 127;
        int gr = row0 + r;
        float4 v = {0.f, 0.f, 0.f, 0.f};
        if (gr < n) v = *(const float4*)&A[gr * K_DIM + k];
        *(float4*)&Asl[r][k] = v;
    }
    __syncthreads();

    int cg = t % CG, rg = t / CG;
    int c0 = cg * 4;
    float acc[RPT][4];
    #pragma unroll
    for (int i = 0; i < RPT; ++i)
        for (int j = 0; j < 4; ++j) acc[i][j] = 0.f;

    for (int k = 0; k < K_DIM; ++k) {
        float4 w = *(const float4*)&W[k * COLS + c0];
        #pragma unroll
        for (int i = 0; i < RPT; ++i) {
            float a = Asl[rg * RPT + i][k];
            acc[i][0] = fmaf(a, w.x, acc[i][0]);
            acc[i][1] = fmaf(a, w.y, acc[i][1]);
            acc[i][2] = fmaf(a, w.z, acc[i][2]);
            acc[i][3] = fmaf(a, w.w, acc[i][3]);
        }
    }

    #pragma unroll
    for (int i = 0; i < RPT; ++i) {
        int r = row0 + rg * RPT + i;
        if (r < n) {
            float s = dinv[r];
            ushort4 o;
            o.x = f2bf(acc[i][0] * s);
            o.y = f2bf(acc[i][1] * s);
            o.z = f2bf(acc[i][2] * s);
            o.w = f2bf(acc[i][3] * s);
            *(ushort4*)&out[r * COLS + c0] = o;
        }
    }
}

// ---------- aggregation: wave = 4 edge-lanes x 16 feat-lanes, 16B/lane ----------

__global__ __launch_bounds__(256) void aggregate128_kernel(const ushort_t* __restrict__ g,
                                                           const int* __restrict__ rowstart,
                                                           const int* __restrict__ csr_src,
                                                           const float* __restrict__ dinv,
                                                           const float* __restrict__ bias,
                                                           float* __restrict__ out, int n) {
    int wave = threadIdx.x >> 6;
    int lane = threadIdx.x & 63;
    int v = blockIdx.x * 4 + wave;
    if (v >= n) return;
    int s    = __builtin_amdgcn_readfirstlane(rowstart[v]);
    int epos = __builtin_amdgcn_readfirstlane(rowstart[v + 1]);
    int eg = lane >> 4;        // edge sub-lane 0..3
    int f  = lane & 15;        // feature group: covers feats f*8..f*8+7

    float a0 = 0.f, a1 = 0.f, a2 = 0.f, a3 = 0.f, a4 = 0.f, a5 = 0.f, a6 = 0.f, a7 = 0.f;
    if (lane < 16) {   // self row
        uint4 m = *(const uint4*)&g[(size_t)v * 128 + f * 8];
        a0 = bf2f_lo(m.x); a1 = bf2f_hi(m.x);
        a2 = bf2f_lo(m.y); a3 = bf2f_hi(m.y);
        a4 = bf2f_lo(m.z); a5 = bf2f_hi(m.z);
        a6 = bf2f_lo(m.w); a7 = bf2f_hi(m.w);
    }

    #pragma unroll 2
    for (int j = s; j < epos; j += 4) {
        int idx = j + eg;
        int safe = min(idx, epos - 1);
        int u = csr_src[safe];
        float w = (idx < epos) ? 1.f : 0.f;
        uint4 m = *(const uint4*)&g[(size_t)u * 128 + f * 8];
        a0 = fmaf(w, bf2f_lo(m.x), a0); a1 = fmaf(w, bf2f_hi(m.x), a1);
        a2 = fmaf(w, bf2f_lo(m.y), a2); a3 = fmaf(w, bf2f_hi(m.y), a3);
        a4 = fmaf(w, bf2f_lo(m.z), a4); a5 = fmaf(w, bf2f_hi(m.z), a5);
        a6 = fmaf(w, bf2f_lo(m.w), a6); a7 = fmaf(w, bf2f_hi(m.w), a7);
    }

    a0 += __shfl_xor(a0, 16); a1 += __shfl_xor(a1, 16);
    a2 += __shfl_xor(a2, 16); a3 += __shfl_xor(a3, 16);
    a4 += __shfl_xor(a4, 16); a5 += __shfl_xor(a5, 16);
    a6 += __shfl_xor(a6, 16); a7 += __shfl_xor(a7, 16);
    a0 += __shfl_xor(a0, 32); a1 += __shfl_xor(a1, 32);
    a2 += __shfl_xor(a2, 32); a3 += __shfl_xor(a3, 32);
    a4 += __shfl_xor(a4, 32); a5 += __shfl_xor(a5, 32);
    a6 += __shfl_xor(a6, 32); a7 += __shfl_xor(a7, 32);

    if (lane < 16) {
        float dv = dinv[v];
        float4 b0 = *(const float4*)&bias[f * 8];
        float4 b1 = *(const float4*)&bias[f * 8 + 4];
        float4 o0 = {fmaxf(fmaf(a0, dv, b0.x), 0.f), fmaxf(fmaf(a1, dv, b0.y), 0.f),
                     fmaxf(fmaf(a2, dv, b0.z), 0.f), fmaxf(fmaf(a3, dv, b0.w), 0.f)};
        float4 o1 = {fmaxf(fmaf(a4, dv, b1.x), 0.f), fmaxf(fmaf(a5, dv, b1.y), 0.f),
                     fmaxf(fmaf(a6, dv, b1.z), 0.f), fmaxf(fmaf(a7, dv, b1.w), 0.f)};
        *(float4*)&out[(size_t)v * 128 + f * 8] = o0;
        *(float4*)&out[(size_t)v * 128 + f * 8 + 4] = o1;
    }
}

// 64-col variant: wave = 8 edge-lanes x 8 feat-lanes
__global__ __launch_bounds__(256) void aggregate64_kernel(const ushort_t* __restrict__ g,
                                                          const int* __restrict__ rowstart,
                                                          const int* __restrict__ csr_src,
                                                          const float* __restrict__ dinv,
                                                          const float* __restrict__ bias,
                                                          float* __restrict__ out, int n) {
    int wave = threadIdx.x >> 6;
    int lane = threadIdx.x & 63;
    int v = blockIdx.x * 4 + wave;
    if (v >= n) return;
    int s    = __builtin_amdgcn_readfirstlane(rowstart[v]);
    int epos = __builtin_amdgcn_readfirstlane(rowstart[v + 1]);
    int eg = lane >> 3;        // edge sub-lane 0..7
    int f  = lane & 7;         // feats f*8..f*8+7

    float a0 = 0.f, a1 = 0.f, a2 = 0.f, a3 = 0.f, a4 = 0.f, a5 = 0.f, a6 = 0.f, a7 = 0.f;
    if (lane < 8) {   // self row
        uint4 m = *(const uint4*)&g[(size_t)v * 64 + f * 8];
        a0 = bf2f_lo(m.x); a1 = bf2f_hi(m.x);
        a2 = bf2f_lo(m.y); a3 = bf2f_hi(m.y);
        a4 = bf2f_lo(m.z); a5 = bf2f_hi(m.z);
        a6 = bf2f_lo(m.w); a7 = bf2f_hi(m.w);
    }

    #pragma unroll 2
    for (int j = s; j < epos; j += 8) {
        int idx = j + eg;
        int safe = min(idx, epos - 1);
        int u = csr_src[safe];
        float w = (idx < epos) ? 1.f : 0.f;
        uint4 m = *(const uint4*)&g[(size_t)u * 64 + f * 8];
        a0 = fmaf(w, bf2f_lo(m.x), a0); a1 = fmaf(w, bf2f_hi(m.x), a1);
        a2 = fmaf(w, bf2f_lo(m.y), a2); a3 = fmaf(w, bf2f_hi(m.y), a3);
        a4 = fmaf(w, bf2f_lo(m.z), a4); a5 = fmaf(w, bf2f_hi(m.z), a5);
        a6 = fmaf(w, bf2f_lo(m.w), a6); a7 = fmaf(w, bf2f_hi(m.w), a7);
    }

    a0 += __shfl_xor(a0, 8);  a1 += __shfl_xor(a1, 8);
    a2 += __shfl_xor(a2, 8);  a3 += __shfl_xor(a3, 8);
    a4 += __shfl_xor(a4, 8);  a5 += __shfl_xor(a5, 8);
    a6 += __shfl_xor(a6, 8);  a7 += __shfl_xor(a7, 8);
    a0 += __shfl_xor(a0, 16); a1 += __shfl_xor(a1, 16);
    a2 += __shfl_xor(a2, 16); a3 += __shfl_xor(a3, 16);
    a4 += __shfl_xor(a4, 16); a5 += __shfl_xor(a5, 16);
    a6 += __shfl_xor(a6, 16); a7 += __shfl_xor(a7, 16);
    a0 += __shfl_xor(a0, 32); a1 += __shfl_xor(a1, 32);
    a2 += __shfl_xor(a2, 32); a3 += __shfl_xor(a3, 32);
    a4 += __shfl_xor(a4, 32); a5 += __shfl_xor(a5, 32);
    a6 += __shfl_xor(a6, 32); a7 += __shfl_xor(a7, 32);

    if (lane < 8) {
        float dv = dinv[v];
        float4 b0 = *(const float4*)&bias[f * 8];
        float4 b1 = *(const float4*)&bias[f * 8 + 4];
        float4 o0 = {fmaxf(fmaf(a0, dv, b0.x), 0.f), fmaxf(fmaf(a1, dv, b0.y), 0.f),
                     fmaxf(fmaf(a2, dv, b0.z), 0.f), fmaxf(fmaf(a3, dv, b0.w), 0.f)};
        float4 o1 = {fmaxf(fmaf(a4, dv, b1.x), 0.f), fmaxf(fmaf(a5, dv, b1.y), 0.f),
                     fmaxf(fmaf(a6, dv, b1.z), 0.f), fmaxf(fmaf(a7, dv, b1.w), 0.f)};
        *(float4*)&out[(size_t)v * 64 + f * 8] = o0;
        *(float4*)&out[(size_t)v * 64 + f * 8 + 4] = o1;
    }
}

extern "C" void kernel_launch(void* const* d_in, const int* in_sizes, int n_in,
                              void* d_out, int out_size, void* d_ws, size_t ws_size,
                              hipStream_t stream) {
    const float* x  = (const float*)d_in[0];
    const int*   ei = (const int*)d_in[1];   // [2, E] int32
    const float* W1 = (const float*)d_in[2];
    const float* b1 = (const float*)d_in[3];
    const float* W2 = (const float*)d_in[4];
    const float* b2 = (const float*)d_in[5];
    float* out = (float*)d_out;

    const int n = in_sizes[0] / 128;   // 50000 (<= 65536 required for packing)
    const int e = in_sizes[1] / 2;     // 800000
    const int* src = ei;
    const int* dst = ei + e;
    const int K   = (n + NPB - 1) / NPB;       // 782 buckets
    const int epb = (e + PB - 1) / PB;         // edges per chunk-block
    const int L   = K * PB;                    // flat histogram length

    char* ws = (char*)d_ws;
    size_t off = 0;
    auto carve = [&](size_t bytes) -> void* {
        void* p = ws + off;
        off = (off + bytes + 255) & ~(size_t)255;
        return p;
    };
    int*      hist     = (int*)     carve((size_t)L * 4);
    int*      bsum     = (int*)     carve((size_t)1024 * 4);
    int*      htotal   = (int*)     carve((size_t)4);
    int*      cnt      = (int*)     carve((size_t)n * 4);
    int*      rowstart = (int*)     carve((size_t)(n + 1) * 4);
    float*    dinv     = (float*)   carve((size_t)n * 4);
    uint_t*   ebuf     = (uint_t*)  carve((size_t)e * 4);
    int*      csr_src  = (int*)     carve((size_t)e * 4);
    ushort_t* g1       = (ushort_t*)carve((size_t)n * 128 * 2);
    float*    h2       = (float*)   carve((size_t)n * 128 * 4);
    ushort_t* g2       = (ushort_t*)carve((size_t)n * 64 * 2);
    (void)ws_size;

    const int nbL = (L + 1023) / 1024;   // hist scan blocks
    const int nbN = (n + 1023) / 1024;   // node scan blocks

    // --- CSR build, zero global atomics, zero memsets ---
    bucket_hist_kernel<<<PB, 256, 0, stream>>>(dst, e, epb, K, hist);
    block_sum_kernel<<<nbL, 256, 0, stream>>>(hist, L, bsum);
    scan_bsum_kernel<<<1, 1024, 0, stream>>>(bsum, nbL, htotal);
    local_scan_apply_kernel<<<nbL, 256, 0, stream>>>(hist, L, bsum);
    partition_kernel<<<PB, 256, 0, stream>>>(src, dst, e, epb, K, hist, ebuf);
    bucket_count_kernel<<<K, 256, 0, stream>>>(ebuf, hist, e, K, n, cnt);
    block_sum_kernel<<<nbN, 256, 0, stream>>>(cnt, n, bsum);
    scan_bsum_kernel<<<1, 1024, 0, stream>>>(bsum, nbN, &rowstart[n]);
    local_scan_kernel<<<nbN, 256, 0, stream>>>(cnt, n, bsum, rowstart, dinv);
    bucket_fill_kernel<<<K, 256, 0, stream>>>(ebuf, hist, rowstart, e, K, n, csr_src);

    // --- layers ---
    const int gblocks = (n + 63) / 64;
    const int ablocks = (n + 3) / 4;
    gemm_scale_kernel<128><<<gblocks, 256, 0, stream>>>(x, W1, dinv, g1, n);
    aggregate128_kernel<<<ablocks, 256, 0, stream>>>(g1, rowstart, csr_src, dinv, b1, h2, n);
    gemm_scale_kernel<64><<<gblocks, 256, 0, stream>>>(h2, W2, dinv, g2, n);
    aggregate64_kernel<<<ablocks, 256, 0, stream>>>(g2, rowstart, csr_src, dinv, b2, out, n);
}

// Round 8
// 158.374 us; speedup vs baseline: 7.0097x; 1.0341x over previous
//
#include <hip/hip_runtime.h>

// GCN 2-layer for MI355X (gfx950). fp32 GEMM, bf16 intermediates, fp32 out.
// out[v] = relu( dinv[v]*( g[v] + sum_{u->v} g[u] ) + b ),  g = dinv .* (x @ W)
//
// R7 baseline (=R4) + two contained changes:
//  1) scan_bsum launches merged into the local-scan kernels (each block
//     redundantly wave-scans the <=98-entry bsum array in LDS). CSR logic
//     (count -> scan -> fill via global memory) unchanged from proven R4.
//  2) GEMM inner loop k-blocked by 4: ds_read_b128 instead of 4x ds_read_b32,
//     same per-output accumulation order (bit-identical results).
// Quarantined: R6's in-kernel shfl-scan rowstart fusion (replay nondeterminism).
// R3 lesson: zero global atomics. R5 lesson: gather-form aggregation only.

#define NPB 64    // nodes per bucket (power of 2)
#define PB  128   // partition chunk-blocks

typedef unsigned short ushort_t;
typedef unsigned int uint_t;

__device__ inline float bf2f_lo(uint_t u) { return __uint_as_float(u << 16); }
__device__ inline float bf2f_hi(uint_t u) { return __uint_as_float(u & 0xffff0000u); }
__device__ inline ushort_t f2bf(float f) {   // round-to-nearest-even
    uint_t x = __float_as_uint(f);
    uint_t r = x + 0x7fffu + ((x >> 16) & 1u);
    return (ushort_t)(r >> 16);
}

// ---------- scan machinery ----------

__global__ __launch_bounds__(256) void block_sum_kernel(const int* __restrict__ a, int L,
                                                        int* __restrict__ bsum) {
    __shared__ int red[256];
    int t = threadIdx.x;
    int base = blockIdx.x * 1024 + t * 4;
    int s = 0;
    if (base + 3 < L) {
        int4 v = *(const int4*)&a[base];
        s = v.x + v.y + v.z + v.w;
    } else {
        for (int i = 0; i < 4; ++i) if (base + i < L) s += a[base + i];
    }
    red[t] = s;
    __syncthreads();
    for (int off = 128; off > 0; off >>= 1) {
        if (t < off) red[t] += red[t + off];
        __syncthreads();
    }
    if (t == 0) bsum[blockIdx.x] = red[0];
}

// Merged: each block redundantly inclusive-scans bsum[0..nb-1] (nb<=256) in LDS,
// then does its local exclusive scan. In-place variant for the flat histogram.
__global__ __launch_bounds__(256) void local_scan_apply_kernel(int* __restrict__ arr, int L,
                                                               const int* __restrict__ bsum,
                                                               int nb) {
    __shared__ int sh[256];
    __shared__ int tsum[256];
    int b = blockIdx.x, t = threadIdx.x;
    sh[t] = (t < nb) ? bsum[t] : 0;
    __syncthreads();
    #pragma unroll
    for (int off = 1; off < 256; off <<= 1) {
        int w = (t >= off) ? sh[t - off] : 0;
        __syncthreads();
        sh[t] += w;
        __syncthreads();
    }
    int bprev = (b == 0) ? 0 : sh[b - 1];

    int base = b * 1024 + t * 4;
    int v[4];
    int s = 0;
    #pragma unroll
    for (int i = 0; i < 4; ++i) {
        int idx = base + i;
        v[i] = (idx < L) ? arr[idx] : 0;
        s += v[i];
    }
    tsum[t] = s;
    __syncthreads();
    for (int off = 1; off < 256; off <<= 1) {
        int w = (t >= off) ? tsum[t - off] : 0;
        __syncthreads();
        tsum[t] += w;
        __syncthreads();
    }
    int excl = (t == 0 ? 0 : tsum[t - 1]) + bprev;
    #pragma unroll
    for (int i = 0; i < 4; ++i) {
        int idx = base + i;
        if (idx < L) {
            arr[idx] = excl;
            excl += v[i];
        }
    }
}

// Merged node variant: cnt -> rowstart + dinv; also writes rowstart[n] = e.
__global__ __launch_bounds__(256) void local_scan_node_kernel(const int* __restrict__ cnt, int n,
                                                              const int* __restrict__ bsum,
                                                              int nb, int e_total,
                                                              int* __restrict__ rowstart,
                                                              float* __restrict__ dinv) {
    __shared__ int sh[256];
    __shared__ int tsum[256];
    int b = blockIdx.x, t = threadIdx.x;
    sh[t] = (t < nb) ? bsum[t] : 0;
    __syncthreads();
    #pragma unroll
    for (int off = 1; off < 256; off <<= 1) {
        int w = (t >= off) ? sh[t - off] : 0;
        __syncthreads();
        sh[t] += w;
        __syncthreads();
    }
    int bprev = (b == 0) ? 0 : sh[b - 1];

    int base = b * 1024 + t * 4;
    int v[4];
    int s = 0;
    #pragma unroll
    for (int i = 0; i < 4; ++i) {
        int idx = base + i;
        v[i] = (idx < n) ? cnt[idx] : 0;
        s += v[i];
    }
    tsum[t] = s;
    __syncthreads();
    for (int off = 1; off < 256; off <<= 1) {
        int w = (t >= off) ? tsum[t - off] : 0;
        __syncthreads();
        tsum[t] += w;
        __syncthreads();
    }
    int excl = (t == 0 ? 0 : tsum[t - 1]) + bprev;
    #pragma unroll
    for (int i = 0; i < 4; ++i) {
        int idx = base + i;
        if (idx < n) {
            rowstart[idx] = excl;
            excl += v[i];
            dinv[idx] = rsqrtf((float)(v[i] + 1));   // +1 self loop
        }
    }
    if (b == 0 && t == 0) rowstart[n] = e_total;
}

// ---------- radix partition (no global atomics) ----------

__global__ __launch_bounds__(256) void bucket_hist_kernel(const int* __restrict__ dst, int e,
                                                          int epb, int K,
                                                          int* __restrict__ hist) {
    __shared__ int lh[1024];
    int t = threadIdx.x, b = blockIdx.x;
    for (int k = t; k < K; k += 256) lh[k] = 0;
    __syncthreads();
    int lo = b * epb, hi = min(lo + epb, e);
    for (int i = lo + t; i < hi; i += 256) atomicAdd(&lh[dst[i] >> 6], 1);
    __syncthreads();
    for (int k = t; k < K; k += 256) hist[k * PB + b] = lh[k];
}

// scatter packed (src | dlocal<<16) into bucket regions (requires n <= 65536)
__global__ __launch_bounds__(256) void partition_kernel(const int* __restrict__ src,
                                                        const int* __restrict__ dst, int e,
                                                        int epb, int K,
                                                        const int* __restrict__ hist,
                                                        uint_t* __restrict__ ebuf) {
    __shared__ int loff[1024];
    int t = threadIdx.x, b = blockIdx.x;
    for (int k = t; k < K; k += 256) loff[k] = hist[k * PB + b];
    __syncthreads();
    int lo = b * epb, hi = min(lo + epb, e);
    for (int i = lo + t; i < hi; i += 256) {
        int d = dst[i];
        int k = d >> 6;
        int pos = atomicAdd(&loff[k], 1);   // LDS atomic only
        ebuf[pos] = (uint_t)src[i] | ((uint_t)(d & (NPB - 1)) << 16);
    }
}

// per-bucket node counts
__global__ __launch_bounds__(256) void bucket_count_kernel(const uint_t* __restrict__ ebuf,
                                                           const int* __restrict__ hist,
                                                           int e, int K, int n,
                                                           int* __restrict__ cnt) {
    __shared__ int c64[NPB];
    int t = threadIdx.x, k = blockIdx.x;
    if (t < NPB) c64[t] = 0;
    __syncthreads();
    int lo = hist[k * PB];
    int hi = (k + 1 < K) ? hist[(k + 1) * PB] : e;
    for (int i = lo + t; i < hi; i += 256) atomicAdd(&c64[(ebuf[i] >> 16) & (NPB - 1)], 1);
    __syncthreads();
    int node = k * NPB + t;
    if (t < NPB && node < n) cnt[node] = c64[t];
}

// per-bucket CSR fill: writes land in the bucket's ~4KB csr window
__global__ __launch_bounds__(256) void bucket_fill_kernel(const uint_t* __restrict__ ebuf,
                                                          const int* __restrict__ hist,
                                                          const int* __restrict__ rowstart,
                                                          int e, int K, int n,
                                                          int* __restrict__ csr_src) {
    __shared__ int rs[NPB];
    __shared__ int c64[NPB];
    int t = threadIdx.x, k = blockIdx.x;
    if (t < NPB) {
        int node = k * NPB + t;
        rs[t] = (node < n) ? rowstart[node] : 0;
        c64[t] = 0;
    }
    __syncthreads();
    int lo = hist[k * PB];
    int hi = (k + 1 < K) ? hist[(k + 1) * PB] : e;
    for (int i = lo + t; i < hi; i += 256) {
        uint_t u = ebuf[i];
        int dl = (u >> 16) & (NPB - 1);
        int slot = rs[dl] + atomicAdd(&c64[dl], 1);   // LDS atomic only
        csr_src[slot] = (int)(u & 0xffffu);
    }
}

// ---------- GEMM: C_bf16[n,COLS] = dinv[row] * (A[n,128] @ W[128,COLS]) ----------
// Inner loop k-blocked by 4: ds_read_b128 for A, 4 batched W float4 loads.
// Per-output accumulation order unchanged (k ascending) -> bit-identical.
#define K_DIM 128
template <int COLS>
__global__ __launch_bounds__(256) void gemm_scale_kernel(const float* __restrict__ A,
                                                         const float* __restrict__ W,
                                                         const float* __restrict__ dinv,
                                                         ushort_t* __restrict__ out, int n) {
    constexpr int CG  = COLS / 4;
    constexpr int RG  = 256 / CG;
    constexpr int RPT = 64 / RG;
    __shared__ float Asl[64][132];   // 132*4B row stride: 16B aligned
    int t    = threadIdx.x;
    int row0 = blockIdx.x * 64;

    #pragma unroll
    for (int it = 0; it < 8; ++it) {
        int idx = (it * 256 + t) * 4;
        int r = idx >> 7;
        int k = idx & 127;
        int gr = row0 + r;
        float4 v = {0.f, 0.f, 0.f, 0.f};
        if (gr < n) v = *(const float4*)&A[gr * K_DIM + k];
        *(float4*)&Asl[r][k] = v;
    }
    __syncthreads();

    int cg = t % CG, rg = t / CG;
    int c0 = cg * 4;
    float acc[RPT][4];
    #pragma unroll
    for (int i = 0; i < RPT; ++i)
        for (int j = 0; j < 4; ++j) acc[i][j] = 0.f;

    const float4* W4 = (const float4*)W;
    constexpr int WS = COLS / 4;   // float4 per W row

    for (int k0 = 0; k0 < K_DIM; k0 += 4) {
        float4 w0 = W4[(k0 + 0) * WS + cg];
        float4 w1 = W4[(k0 + 1) * WS + cg];
        float4 w2 = W4[(k0 + 2) * WS + cg];
        float4 w3 = W4[(k0 + 3) * WS + cg];
        #pragma unroll
        for (int i = 0; i < RPT; ++i) {
            float4 a = *(const float4*)&Asl[rg * RPT + i][k0];
            acc[i][0] = fmaf(a.x, w0.x, acc[i][0]);
            acc[i][1] = fmaf(a.x, w0.y, acc[i][1]);
            acc[i][2] = fmaf(a.x, w0.z, acc[i][2]);
            acc[i][3] = fmaf(a.x, w0.w, acc[i][3]);
            acc[i][0] = fmaf(a.y, w1.x, acc[i][0]);
            acc[i][1] = fmaf(a.y, w1.y, acc[i][1]);
            acc[i][2] = fmaf(a.y, w1.z, acc[i][2]);
            acc[i][3] = fmaf(a.y, w1.w, acc[i][3]);
            acc[i][0] = fmaf(a.z, w2.x, acc[i][0]);
            acc[i][1] = fmaf(a.z, w2.y, acc[i][1]);
            acc[i][2] = fmaf(a.z, w2.z, acc[i][2]);
            acc[i][3] = fmaf(a.z, w2.w, acc[i][3]);
            acc[i][0] = fmaf(a.w, w3.x, acc[i][0]);
            acc[i][1] = fmaf(a.w, w3.y, acc[i][1]);
            acc[i][2] = fmaf(a.w, w3.z, acc[i][2]);
            acc[i][3] = fmaf(a.w, w3.w, acc[i][3]);
        }
    }

    #pragma unroll
    for (int i = 0; i < RPT; ++i) {
        int r = row0 + rg * RPT + i;
        if (r < n) {
            float s = dinv[r];
            ushort4 o;
            o.x = f2bf(acc[i][0] * s);
            o.y = f2bf(acc[i][1] * s);
            o.z = f2bf(acc[i][2] * s);
            o.w = f2bf(acc[i][3] * s);
            *(ushort4*)&out[r * COLS + c0] = o;
        }
    }
}

// ---------- aggregation (R4-proven): wave = edge-lanes x feat-lanes, 16B/lane ----------

__global__ __launch_bounds__(256) void aggregate128_kernel(const ushort_t* __restrict__ g,
                                                           const int* __restrict__ rowstart,
                                                           const int* __restrict__ csr_src,
                                                           const float* __restrict__ dinv,
                                                           const float* __restrict__ bias,
                                                           float* __restrict__ out, int n) {
    int wave = threadIdx.x >> 6;
    int lane = threadIdx.x & 63;
    int v = blockIdx.x * 4 + wave;
    if (v >= n) return;
    int s    = __builtin_amdgcn_readfirstlane(rowstart[v]);
    int epos = __builtin_amdgcn_readfirstlane(rowstart[v + 1]);
    int eg = lane >> 4;        // edge sub-lane 0..3
    int f  = lane & 15;        // feature group (8 feats = 16B)

    float a0 = 0.f, a1 = 0.f, a2 = 0.f, a3 = 0.f, a4 = 0.f, a5 = 0.f, a6 = 0.f, a7 = 0.f;
    if (lane < 16) {   // self row
        uint4 m = *(const uint4*)&g[(size_t)v * 128 + f * 8];
        a0 = bf2f_lo(m.x); a1 = bf2f_hi(m.x);
        a2 = bf2f_lo(m.y); a3 = bf2f_hi(m.y);
        a4 = bf2f_lo(m.z); a5 = bf2f_hi(m.z);
        a6 = bf2f_lo(m.w); a7 = bf2f_hi(m.w);
    }

    #pragma unroll 2
    for (int j = s; j < epos; j += 4) {
        int idx = j + eg;
        int safe = min(idx, epos - 1);
        int u = csr_src[safe];
        float w = (idx < epos) ? 1.f : 0.f;
        uint4 m = *(const uint4*)&g[(size_t)u * 128 + f * 8];
        a0 = fmaf(w, bf2f_lo(m.x), a0); a1 = fmaf(w, bf2f_hi(m.x), a1);
        a2 = fmaf(w, bf2f_lo(m.y), a2); a3 = fmaf(w, bf2f_hi(m.y), a3);
        a4 = fmaf(w, bf2f_lo(m.z), a4); a5 = fmaf(w, bf2f_hi(m.z), a5);
        a6 = fmaf(w, bf2f_lo(m.w), a6); a7 = fmaf(w, bf2f_hi(m.w), a7);
    }

    a0 += __shfl_xor(a0, 16); a1 += __shfl_xor(a1, 16);
    a2 += __shfl_xor(a2, 16); a3 += __shfl_xor(a3, 16);
    a4 += __shfl_xor(a4, 16); a5 += __shfl_xor(a5, 16);
    a6 += __shfl_xor(a6, 16); a7 += __shfl_xor(a7, 16);
    a0 += __shfl_xor(a0, 32); a1 += __shfl_xor(a1, 32);
    a2 += __shfl_xor(a2, 32); a3 += __shfl_xor(a3, 32);
    a4 += __shfl_xor(a4, 32); a5 += __shfl_xor(a5, 32);
    a6 += __shfl_xor(a6, 32); a7 += __shfl_xor(a7, 32);

    if (lane < 16) {
        float dv = dinv[v];
        float4 b0 = *(const float4*)&bias[f * 8];
        float4 b1 = *(const float4*)&bias[f * 8 + 4];
        float4 o0 = {fmaxf(fmaf(a0, dv, b0.x), 0.f), fmaxf(fmaf(a1, dv, b0.y), 0.f),
                     fmaxf(fmaf(a2, dv, b0.z), 0.f), fmaxf(fmaf(a3, dv, b0.w), 0.f)};
        float4 o1 = {fmaxf(fmaf(a4, dv, b1.x), 0.f), fmaxf(fmaf(a5, dv, b1.y), 0.f),
                     fmaxf(fmaf(a6, dv, b1.z), 0.f), fmaxf(fmaf(a7, dv, b1.w), 0.f)};
        *(float4*)&out[(size_t)v * 128 + f * 8] = o0;
        *(float4*)&out[(size_t)v * 128 + f * 8 + 4] = o1;
    }
}

__global__ __launch_bounds__(256) void aggregate64_kernel(const ushort_t* __restrict__ g,
                                                          const int* __restrict__ rowstart,
                                                          const int* __restrict__ csr_src,
                                                          const float* __restrict__ dinv,
                                                          const float* __restrict__ bias,
                                                          float* __restrict__ out, int n) {
    int wave = threadIdx.x >> 6;
    int lane = threadIdx.x & 63;
    int v = blockIdx.x * 4 + wave;
    if (v >= n) return;
    int s    = __builtin_amdgcn_readfirstlane(rowstart[v]);
    int epos = __builtin_amdgcn_readfirstlane(rowstart[v + 1]);
    int eg = lane >> 3;        // edge sub-lane 0..7
    int f  = lane & 7;         // feats f*8..f*8+7

    float a0 = 0.f, a1 = 0.f, a2 = 0.f, a3 = 0.f, a4 = 0.f, a5 = 0.f, a6 = 0.f, a7 = 0.f;
    if (lane < 8) {   // self row
        uint4 m = *(const uint4*)&g[(size_t)v * 64 + f * 8];
        a0 = bf2f_lo(m.x); a1 = bf2f_hi(m.x);
        a2 = bf2f_lo(m.y); a3 = bf2f_hi(m.y);
        a4 = bf2f_lo(m.z); a5 = bf2f_hi(m.z);
        a6 = bf2f_lo(m.w); a7 = bf2f_hi(m.w);
    }

    #pragma unroll 2
    for (int j = s; j < epos; j += 8) {
        int idx = j + eg;
        int safe = min(idx, epos - 1);
        int u = csr_src[safe];
        float w = (idx < epos) ? 1.f : 0.f;
        uint4 m = *(const uint4*)&g[(size_t)u * 64 + f * 8];
        a0 = fmaf(w, bf2f_lo(m.x), a0); a1 = fmaf(w, bf2f_hi(m.x), a1);
        a2 = fmaf(w, bf2f_lo(m.y), a2); a3 = fmaf(w, bf2f_hi(m.y), a3);
        a4 = fmaf(w, bf2f_lo(m.z), a4); a5 = fmaf(w, bf2f_hi(m.z), a5);
        a6 = fmaf(w, bf2f_lo(m.w), a6); a7 = fmaf(w, bf2f_hi(m.w), a7);
    }

    a0 += __shfl_xor(a0, 8);  a1 += __shfl_xor(a1, 8);
    a2 += __shfl_xor(a2, 8);  a3 += __shfl_xor(a3, 8);
    a4 += __shfl_xor(a4, 8);  a5 += __shfl_xor(a5, 8);
    a6 += __shfl_xor(a6, 8);  a7 += __shfl_xor(a7, 8);
    a0 += __shfl_xor(a0, 16); a1 += __shfl_xor(a1, 16);
    a2 += __shfl_xor(a2, 16); a3 += __shfl_xor(a3, 16);
    a4 += __shfl_xor(a4, 16); a5 += __shfl_xor(a5, 16);
    a6 += __shfl_xor(a6, 16); a7 += __shfl_xor(a7, 16);
    a0 += __shfl_xor(a0, 32); a1 += __shfl_xor(a1, 32);
    a2 += __shfl_xor(a2, 32); a3 += __shfl_xor(a3, 32);
    a4 += __shfl_xor(a4, 32); a5 += __shfl_xor(a5, 32);
    a6 += __shfl_xor(a6, 32); a7 += __shfl_xor(a7, 32);

    if (lane < 8) {
        float dv = dinv[v];
        float4 b0 = *(const float4*)&bias[f * 8];
        float4 b1 = *(const float4*)&bias[f * 8 + 4];
        float4 o0 = {fmaxf(fmaf(a0, dv, b0.x), 0.f), fmaxf(fmaf(a1, dv, b0.y), 0.f),
                     fmaxf(fmaf(a2, dv, b0.z), 0.f), fmaxf(fmaf(a3, dv, b0.w), 0.f)};
        float4 o1 = {fmaxf(fmaf(a4, dv, b1.x), 0.f), fmaxf(fmaf(a5, dv, b1.y), 0.f),
                     fmaxf(fmaf(a6, dv, b1.z), 0.f), fmaxf(fmaf(a7, dv, b1.w), 0.f)};
        *(float4*)&out[(size_t)v * 64 + f * 8] = o0;
        *(float4*)&out[(size_t)v * 64 + f * 8 + 4] = o1;
    }
}

extern "C" void kernel_launch(void* const* d_in, const int* in_sizes, int n_in,
                              void* d_out, int out_size, void* d_ws, size_t ws_size,
                              hipStream_t stream) {
    const float* x  = (const float*)d_in[0];
    const int*   ei = (const int*)d_in[1];   // [2, E] int32
    const float* W1 = (const float*)d_in[2];
    const float* b1 = (const float*)d_in[3];
    const float* W2 = (const float*)d_in[4];
    const float* b2 = (const float*)d_in[5];
    float* out = (float*)d_out;

    const int n = in_sizes[0] / 128;   // 50000 (<= 65536 required for packing)
    const int e = in_sizes[1] / 2;     // 800000
    const int* src = ei;
    const int* dst = ei + e;
    const int K   = (n + NPB - 1) / NPB;       // 782 buckets
    const int epb = (e + PB - 1) / PB;         // edges per chunk-block
    const int L   = K * PB;                    // flat histogram length

    char* ws = (char*)d_ws;
    size_t off = 0;
    auto carve = [&](size_t bytes) -> void* {
        void* p = ws + off;
        off = (off + bytes + 255) & ~(size_t)255;
        return p;
    };
    int*      hist     = (int*)     carve((size_t)L * 4);
    int*      bsum     = (int*)     carve((size_t)1024 * 4);
    int*      cnt      = (int*)     carve((size_t)n * 4);
    int*      rowstart = (int*)     carve((size_t)(n + 1) * 4);
    float*    dinv     = (float*)   carve((size_t)n * 4);
    uint_t*   ebuf     = (uint_t*)  carve((size_t)e * 4);
    int*      csr_src  = (int*)     carve((size_t)e * 4);
    ushort_t* g1       = (ushort_t*)carve((size_t)n * 128 * 2);
    float*    h2       = (float*)   carve((size_t)n * 128 * 4);
    ushort_t* g2       = (ushort_t*)carve((size_t)n * 64 * 2);
    (void)ws_size;

    const int nbL = (L + 1023) / 1024;   // hist scan blocks (<=256 required)
    const int nbN = (n + 1023) / 1024;   // node scan blocks (<=256 required)

    // --- CSR build, zero global atomics, zero memsets, 8 launches ---
    bucket_hist_kernel<<<PB, 256, 0, stream>>>(dst, e, epb, K, hist);
    block_sum_kernel<<<nbL, 256, 0, stream>>>(hist, L, bsum);
    local_scan_apply_kernel<<<nbL, 256, 0, stream>>>(hist, L, bsum, nbL);
    partition_kernel<<<PB, 256, 0, stream>>>(src, dst, e, epb, K, hist, ebuf);
    bucket_count_kernel<<<K, 256, 0, stream>>>(ebuf, hist, e, K, n, cnt);
    block_sum_kernel<<<nbN, 256, 0, stream>>>(cnt, n, bsum);
    local_scan_node_kernel<<<nbN, 256, 0, stream>>>(cnt, n, bsum, nbN, e, rowstart, dinv);
    bucket_fill_kernel<<<K, 256, 0, stream>>>(ebuf, hist, rowstart, e, K, n, csr_src);

    // --- layers ---
    const int gblocks = (n + 63) / 64;
    const int ablocks = (n + 3) / 4;
    gemm_scale_kernel<128><<<gblocks, 256, 0, stream>>>(x, W1, dinv, g1, n);
    aggregate128_kernel<<<ablocks, 256, 0, stream>>>(g1, rowstart, csr_src, dinv, b1, h2, n);
    gemm_scale_kernel<64><<<gblocks, 256, 0, stream>>>(h2, W2, dinv, g2, n);
    aggregate64_kernel<<<ablocks, 256, 0, stream>>>(g2, rowstart, csr_src, dinv, b2, out, n);
}